// Round 12
// baseline (150.569 us; speedup 1.0000x reference)
//
#include <hip/hip_runtime.h>

// G=256, B=4. Parent/ref coords are even -> compressed key k23=(b,x/2,y/2,z/2)
// in 2^23 (1 MB bitmap). Monotone bijection => same sorted-unique order as ref.
#define WORDS_P  (1u << 18)   // 2^23 / 32
#define NBLK2    1024         // 1024 blocks * 256 words = WORDS_P

typedef float f4_native __attribute__((ext_vector_type(4)));

__device__ __forceinline__ unsigned k23_of(int b, int x, int y, int z) {
  return ((unsigned)b << 21) | ((unsigned)(x >> 1) << 14) |
         ((unsigned)(y >> 1) << 7) | (unsigned)(z >> 1);
}

// ---- fused fill: parbm+refbm (2 MB) = 0, out feats+mask (260 MB) = 0 ----
__global__ __launch_bounds__(256) void fill_all(f4_native* __restrict__ wsz, size_t n4_ws,
                                                f4_native* __restrict__ ofm, size_t n4_ofm) {
  size_t stride = (size_t)gridDim.x * 256u;
  size_t i0 = (size_t)blockIdx.x * 256u + threadIdx.x;
  f4_native z = {0.f, 0.f, 0.f, 0.f};
  size_t total = n4_ws + n4_ofm;
  for (size_t i = i0; i < total; i += stride) {
    if (i < n4_ws) wsz[i] = z;
    else __builtin_nontemporal_store(z, &ofm[i - n4_ws]);
  }
}

// ---- build parent + ref bitmaps (block-range partition) ----
__global__ __launch_bounds__(256) void build_bm(const int4* __restrict__ coords, int n,
                                                const int4* __restrict__ ref, int nref,
                                                unsigned* __restrict__ parbm,
                                                unsigned* __restrict__ refbm, int nbN) {
  if ((int)blockIdx.x < nbN) {
    int i = blockIdx.x * 256 + threadIdx.x;
    if (i >= n) return;
    int4 c = coords[i];                     // (b,x,y,z)
    unsigned k = k23_of(c.x, c.y, c.z, c.w);
    atomicOr(&parbm[k >> 5], 1u << (k & 31));
  } else {
    int i = (blockIdx.x - nbN) * 256 + threadIdx.x;
    if (i >= nref) return;
    int4 c = ref[i];                        // even coords on stride-2 grid
    unsigned k = k23_of(c.x, c.y, c.z, c.w);
    atomicOr(&refbm[k >> 5], 1u << (k & 31));
  }
}

// ---- maskbm = parbm & refbm (in place over refbm) + block sums for both ----
__global__ __launch_bounds__(256) void pop2(const unsigned* __restrict__ parbm,
                                            unsigned* __restrict__ refbm,
                                            unsigned* __restrict__ bsums) {
  __shared__ unsigned s[256];
  unsigned t = threadIdx.x;
  unsigned w = blockIdx.x * 256u + t;
  unsigned p = parbm[w];
  unsigned m = p & refbm[w];
  refbm[w] = m;                              // refbm becomes maskbm
  s[t] = __popc(p); __syncthreads();
  for (int off = 128; off > 0; off >>= 1) { if (t < (unsigned)off) s[t] += s[t + off]; __syncthreads(); }
  if (t == 0) bsums[blockIdx.x] = s[0];
  __syncthreads();
  s[t] = __popc(m); __syncthreads();
  for (int off = 128; off > 0; off >>= 1) { if (t < (unsigned)off) s[t] += s[t + off]; __syncthreads(); }
  if (t == 0) bsums[NBLK2 + blockIdx.x] = s[0];
}

// ---- per-word prefixes; each block self-scans bsums (L2-hot); zero used clist;
//      block NBLK2-1 publishes totals: counter[0]=M (masked), counter[1]=P (parents) ----
__global__ __launch_bounds__(256) void prefix2b(const unsigned* __restrict__ parbm,
                                                const unsigned* __restrict__ maskbm,
                                                const unsigned* __restrict__ bsums,
                                                unsigned* __restrict__ parpre,
                                                unsigned* __restrict__ maskpre,
                                                unsigned* __restrict__ clist,
                                                unsigned* __restrict__ counter) {
  __shared__ unsigned s[256];
  __shared__ unsigned basP_s, basM_s;
  unsigned t = threadIdx.x, blk = blockIdx.x;
  // block base offsets: sum bsums[0..blk) for both arrays
  unsigned accP = 0, accM = 0;
  for (unsigned idx = t; idx < blk; idx += 256u) {
    accP += bsums[idx];
    accM += bsums[NBLK2 + idx];
  }
  s[t] = accP; __syncthreads();
  for (int off = 128; off > 0; off >>= 1) { if (t < (unsigned)off) s[t] += s[t + off]; __syncthreads(); }
  if (t == 0) basP_s = s[0];
  __syncthreads();
  s[t] = accM; __syncthreads();
  for (int off = 128; off > 0; off >>= 1) { if (t < (unsigned)off) s[t] += s[t + off]; __syncthreads(); }
  if (t == 0) basM_s = s[0];
  __syncthreads();
  unsigned basP = basP_s, basM = basM_s;

  unsigned w = blk * 256u + t;
  unsigned pw = parbm[w], mw = maskbm[w];
  unsigned cp = __popc(pw), cm = __popc(mw);
  // in-block exclusive scan of cp
  s[t] = cp; __syncthreads();
  for (int off = 1; off < 256; off <<= 1) {
    unsigned v = (t >= (unsigned)off) ? s[t - off] : 0u;
    __syncthreads(); s[t] += v; __syncthreads();
  }
  unsigned ppre = basP + ((t == 0) ? 0u : s[t - 1]);
  parpre[w] = ppre;
  unsigned plast = basP + s[255];
  __syncthreads();
  // in-block exclusive scan of cm
  s[t] = cm; __syncthreads();
  for (int off = 1; off < 256; off <<= 1) {
    unsigned v = (t >= (unsigned)off) ? s[t - off] : 0u;
    __syncthreads(); s[t] += v; __syncthreads();
  }
  unsigned mpre = basM + ((t == 0) ? 0u : s[t - 1]);
  maskpre[w] = mpre;
  // zero exactly the clist slots this word's masked parents will use
  for (unsigned k = 0; k < cm * 8u; k++) clist[mpre * 8u + k] = 0u;
  if (blk == NBLK2 - 1u && t == 255u) {
    counter[0] = basM + s[255];              // M: total masked parents
    counter[1] = plast;                      // P: total parents
  }
}

// ---- fused: input->clist scatter [0,nbN) + emit [nbN,nbN+1024) + coords tail fill ----
// clist slot (maskrank*8 + childoff) is UNIQUE per input -> no atomics, deterministic.
__global__ __launch_bounds__(256) void scatter_emit(const int4* __restrict__ coords, int n,
                                                    const unsigned* __restrict__ parbm,
                                                    const unsigned* __restrict__ parpre,
                                                    const unsigned* __restrict__ maskbm,
                                                    const unsigned* __restrict__ maskpre,
                                                    const unsigned* __restrict__ counter,
                                                    unsigned* __restrict__ clist,
                                                    unsigned* __restrict__ mrow,
                                                    float4* __restrict__ out_coords,
                                                    float* __restrict__ out_mask,
                                                    int nbN) {
  if ((int)blockIdx.x < nbN) {
    int i = blockIdx.x * 256 + threadIdx.x;
    if (i >= n) return;
    int4 c = coords[i];
    unsigned k = k23_of(c.x, c.y, c.z, c.w);
    unsigned w = k >> 5, b = k & 31u;
    unsigned mw = maskbm[w];
    if ((mw >> b) & 1u) {
      unsigned j = maskpre[w] + __popc(mw & ((1u << b) - 1u));
      unsigned off = (((unsigned)c.y & 1u) << 2) | (((unsigned)c.z & 1u) << 1) |
                     ((unsigned)c.w & 1u);
      clist[j * 8u + off] = (unsigned)i + 1u;  // row + 1 (0 = absent)
    }
    return;
  }
  if ((int)blockIdx.x < nbN + (int)NBLK2) {
    unsigned w = (blockIdx.x - nbN) * 256u + threadIdx.x;
    unsigned bits = parbm[w];
    if (!bits) return;
    unsigned mb = maskbm[w];
    unsigned r = parpre[w];
    unsigned j = maskpre[w];
    while (bits) {
      unsigned b = (unsigned)__ffs((int)bits) - 1u;
      bits &= bits - 1u;
      unsigned k = (w << 5) | b;
      float bb = (float)(k >> 21);
      float x = (float)(((k >> 14) & 127u) << 1);
      float y = (float)(((k >> 7) & 127u) << 1);
      float z = (float)((k & 127u) << 1);
      out_coords[r] = make_float4(bb, x, y, z);
      if ((mb >> b) & 1u) {
        out_mask[r] = 1.0f;
        mrow[j++] = r;
      }
      r++;
    }
    return;
  }
  // tail: rows [P, N) get coords = -1
  unsigned P = counter[1];
  unsigned idx = (blockIdx.x - nbN - NBLK2) * 256u + threadIdx.x;
  unsigned ntail = (unsigned)n - P;
  float4 m1 = make_float4(-1.f, -1.f, -1.f, -1.f);
  for (unsigned i = idx; i < ntail; i += 64u * 256u) out_coords[P + i] = m1;
}

// ---- conv: W in LDS; one wave per masked parent; children direct from clist ----
// 1024 threads (16 waves), 64 KB LDS -> 2 blocks/CU; min 8 waves/EU.
__global__ __launch_bounds__(1024, 8) void conv_lds(const float* __restrict__ feats,
                                                    const float* __restrict__ Wg,
                                                    const float* __restrict__ bias,
                                                    const unsigned* __restrict__ clist,
                                                    const unsigned* __restrict__ mrow,
                                                    const unsigned* __restrict__ counter,
                                                    float* __restrict__ out_feats) {
  __shared__ float lw[16384];                // all of W: 8*32*64 floats = 64 KB
  for (unsigned t = threadIdx.x; t < 4096u; t += 1024u)
    ((float4*)lw)[t] = ((const float4*)Wg)[t];
  __syncthreads();

  unsigned lane = threadIdx.x & 63u;
  unsigned wave = blockIdx.x * 16u + (threadIdx.x >> 6);
  unsigned nwaves = gridDim.x * 16u;
  unsigned M = counter[0];
  float bv = bias[lane];
  for (unsigned j = wave; j < M; j += nwaves) {
    unsigned r = mrow[j];                    // uniform load -> broadcast
    uint4 c0 = *(const uint4*)(clist + (size_t)j * 8u);
    uint4 c1 = *(const uint4*)(clist + (size_t)j * 8u + 4u);
    unsigned cs[8] = {c0.x, c0.y, c0.z, c0.w, c1.x, c1.y, c1.z, c1.w};
    float acc = bv;
#pragma unroll
    for (int i = 0; i < 8; i++) {
      unsigned v = (unsigned)__builtin_amdgcn_readfirstlane((int)cs[i]);
      if (v) {                               // wave-uniform branch
        const float* f = feats + (size_t)(v - 1u) * 32u;   // SGPR base -> s_load
        const float* wl = lw + i * 2048 + lane;
#pragma unroll
        for (int k = 0; k < 32; k++) acc = fmaf(f[k], wl[k * 64], acc);
      }
    }
    out_feats[(size_t)r * 64u + lane] = acc;
  }
}

extern "C" void kernel_launch(void* const* d_in, const int* in_sizes, int n_in,
                              void* d_out, int out_size, void* d_ws, size_t ws_size,
                              hipStream_t stream) {
  const float* feats = (const float*)d_in[0];
  const float* W     = (const float*)d_in[1];
  const float* bias  = (const float*)d_in[2];
  const int4*  coords = (const int4*)d_in[3];
  const int4*  ref    = (const int4*)d_in[4];
  int N    = in_sizes[0] / 32;
  int NREF = in_sizes[4] / 4;

  float* out_coords = (float*)d_out;
  float* out_feats  = out_coords + (size_t)N * 4;
  float* out_mask   = out_feats + (size_t)N * 64;

  char* ws = (char*)d_ws;
  unsigned* parbm   = (unsigned*)(ws);                    // 1 MB
  unsigned* refbm   = (unsigned*)(ws + (1u << 20));       // 1 MB (becomes maskbm)
  unsigned* maskbm  = refbm;
  unsigned* clist   = (unsigned*)(ws + (2u << 20));       // 13 MB (used: M*8 u32)
  unsigned* parpre  = (unsigned*)(ws + (15u << 20));      // 1 MB
  unsigned* maskpre = (unsigned*)(ws + (16u << 20));      // 1 MB
  unsigned* mrow    = (unsigned*)(ws + (17u << 20));      // 2 MB (M u32 used)
  unsigned* bsums   = (unsigned*)(ws + (19u << 20));            // 2*1024 u32
  unsigned* counter = (unsigned*)(ws + (19u << 20) + 16384);    // 2 u32

  int nbN = (N + 255) / 256;
  int nbR = (NREF + 255) / 256;

  // 1) fill: parbm+refbm (2 MB) = 0, out feats+mask (260 MB) = 0
  fill_all<<<2048, 256, 0, stream>>>((f4_native*)ws, (size_t)(2u << 20) / 16u,
                                     (f4_native*)out_feats, (size_t)N * 65u * 4u / 16u);
  // 2) bitmaps
  build_bm<<<nbN + nbR, 256, 0, stream>>>(coords, N, ref, NREF, parbm, refbm, nbN);
  // 3) popcount block sums + mask AND
  pop2<<<NBLK2, 256, 0, stream>>>(parbm, refbm, bsums);
  // 4) prefixes (self-scanned) + clist zero + totals
  prefix2b<<<NBLK2, 256, 0, stream>>>(parbm, maskbm, bsums, parpre, maskpre, clist,
                                      counter);
  // 5) input->clist scatter + emit coords/mask/mrow + coords tail fill
  scatter_emit<<<nbN + NBLK2 + 64, 256, 0, stream>>>(coords, N, parbm, parpre, maskbm,
                                                     maskpre, counter, clist, mrow,
                                                     (float4*)out_coords, out_mask, nbN);
  // 6) conv
  conv_lds<<<512, 1024, 0, stream>>>(feats, W, bias, clist, mrow, counter, out_feats);
}

// Round 13
// 130.456 us; speedup vs baseline: 1.1542x; 1.1542x over previous
//
#include <hip/hip_runtime.h>

// G=256, B=4. Parent/ref coords are even -> compressed key k23=(b,x/2,y/2,z/2)
// in 2^23 (1 MB bitmap). Monotone bijection => same sorted-unique order as ref.
#define WORDS_P  (1u << 18)   // 2^23 / 32
#define NBLK2    1024         // 1024 blocks * 256 words = WORDS_P

typedef float f4_native __attribute__((ext_vector_type(4)));

__device__ __forceinline__ unsigned k23_of(int b, int x, int y, int z) {
  return ((unsigned)b << 21) | ((unsigned)(x >> 1) << 14) |
         ((unsigned)(y >> 1) << 7) | (unsigned)(z >> 1);
}

// ---- tiny fill: parbm+refbm (2 MB) = 0 (must precede build's atomicOr) ----
__global__ __launch_bounds__(256) void fill_ws(f4_native* __restrict__ wsz, size_t n4) {
  size_t stride = (size_t)gridDim.x * 256u;
  f4_native z = {0.f, 0.f, 0.f, 0.f};
  for (size_t i = (size_t)blockIdx.x * 256u + threadIdx.x; i < n4; i += stride)
    wsz[i] = z;
}

// ---- fused: bitmap build (atomics) + 264 MB out feats+mask zero-fill ----
// The fill only needs to complete before conv (stage 6); fusing it here hides the
// ~6 us of atomic work inside the ~40 us fill instead of serializing stages.
__global__ __launch_bounds__(256) void build_fill(const int4* __restrict__ coords, int n,
                                                  const int4* __restrict__ ref, int nref,
                                                  unsigned* __restrict__ parbm,
                                                  unsigned* __restrict__ refbm,
                                                  f4_native* __restrict__ ofm,
                                                  size_t n4_ofm) {
  unsigned tid = blockIdx.x * 256u + threadIdx.x;
  unsigned nthr = gridDim.x * 256u;
  for (unsigned i = tid; i < (unsigned)(n + nref); i += nthr) {
    if (i < (unsigned)n) {
      int4 c = coords[i];                   // (b,x,y,z)
      unsigned k = k23_of(c.x, c.y, c.z, c.w);
      atomicOr(&parbm[k >> 5], 1u << (k & 31));
    } else {
      int4 c = ref[i - (unsigned)n];        // even coords on stride-2 grid
      unsigned k = k23_of(c.x, c.y, c.z, c.w);
      atomicOr(&refbm[k >> 5], 1u << (k & 31));
    }
  }
  f4_native z = {0.f, 0.f, 0.f, 0.f};
  for (size_t i = tid; i < n4_ofm; i += nthr)
    __builtin_nontemporal_store(z, &ofm[i]);
}

// ---- maskbm = parbm & refbm (in place over refbm) + block sums for both ----
__global__ __launch_bounds__(256) void pop2(const unsigned* __restrict__ parbm,
                                            unsigned* __restrict__ refbm,
                                            unsigned* __restrict__ bsums) {
  __shared__ unsigned s[256];
  unsigned t = threadIdx.x;
  unsigned w = blockIdx.x * 256u + t;
  unsigned p = parbm[w];
  unsigned m = p & refbm[w];
  refbm[w] = m;                              // refbm becomes maskbm
  s[t] = __popc(p); __syncthreads();
  for (int off = 128; off > 0; off >>= 1) { if (t < (unsigned)off) s[t] += s[t + off]; __syncthreads(); }
  if (t == 0) bsums[blockIdx.x] = s[0];
  __syncthreads();
  s[t] = __popc(m); __syncthreads();
  for (int off = 128; off > 0; off >>= 1) { if (t < (unsigned)off) s[t] += s[t + off]; __syncthreads(); }
  if (t == 0) bsums[NBLK2 + blockIdx.x] = s[0];
}

// ---- per-word prefixes; each block self-scans bsums (L2-hot); zero used clist;
//      block NBLK2-1 publishes totals: counter[0]=M (masked), counter[1]=P (parents) ----
__global__ __launch_bounds__(256) void prefix2b(const unsigned* __restrict__ parbm,
                                                const unsigned* __restrict__ maskbm,
                                                const unsigned* __restrict__ bsums,
                                                unsigned* __restrict__ parpre,
                                                unsigned* __restrict__ maskpre,
                                                unsigned* __restrict__ clist,
                                                unsigned* __restrict__ counter) {
  __shared__ unsigned s[256];
  __shared__ unsigned basP_s, basM_s;
  unsigned t = threadIdx.x, blk = blockIdx.x;
  unsigned accP = 0, accM = 0;
  for (unsigned idx = t; idx < blk; idx += 256u) {
    accP += bsums[idx];
    accM += bsums[NBLK2 + idx];
  }
  s[t] = accP; __syncthreads();
  for (int off = 128; off > 0; off >>= 1) { if (t < (unsigned)off) s[t] += s[t + off]; __syncthreads(); }
  if (t == 0) basP_s = s[0];
  __syncthreads();
  s[t] = accM; __syncthreads();
  for (int off = 128; off > 0; off >>= 1) { if (t < (unsigned)off) s[t] += s[t + off]; __syncthreads(); }
  if (t == 0) basM_s = s[0];
  __syncthreads();
  unsigned basP = basP_s, basM = basM_s;

  unsigned w = blk * 256u + t;
  unsigned pw = parbm[w], mw = maskbm[w];
  unsigned cp = __popc(pw), cm = __popc(mw);
  s[t] = cp; __syncthreads();
  for (int off = 1; off < 256; off <<= 1) {
    unsigned v = (t >= (unsigned)off) ? s[t - off] : 0u;
    __syncthreads(); s[t] += v; __syncthreads();
  }
  unsigned ppre = basP + ((t == 0) ? 0u : s[t - 1]);
  parpre[w] = ppre;
  unsigned plast = basP + s[255];
  __syncthreads();
  s[t] = cm; __syncthreads();
  for (int off = 1; off < 256; off <<= 1) {
    unsigned v = (t >= (unsigned)off) ? s[t - off] : 0u;
    __syncthreads(); s[t] += v; __syncthreads();
  }
  unsigned mpre = basM + ((t == 0) ? 0u : s[t - 1]);
  maskpre[w] = mpre;
  for (unsigned k = 0; k < cm * 8u; k++) clist[mpre * 8u + k] = 0u;
  if (blk == NBLK2 - 1u && t == 255u) {
    counter[0] = basM + s[255];              // M: total masked parents
    counter[1] = plast;                      // P: total parents
  }
}

// ---- fused: input->clist scatter [0,nbN) + emit [nbN,nbN+1024) + coords tail fill ----
// clist slot (maskrank*8 + childoff) is UNIQUE per input -> no atomics, deterministic.
__global__ __launch_bounds__(256) void scatter_emit(const int4* __restrict__ coords, int n,
                                                    const unsigned* __restrict__ parbm,
                                                    const unsigned* __restrict__ parpre,
                                                    const unsigned* __restrict__ maskbm,
                                                    const unsigned* __restrict__ maskpre,
                                                    const unsigned* __restrict__ counter,
                                                    unsigned* __restrict__ clist,
                                                    unsigned* __restrict__ mrow,
                                                    float4* __restrict__ out_coords,
                                                    float* __restrict__ out_mask,
                                                    int nbN) {
  if ((int)blockIdx.x < nbN) {
    int i = blockIdx.x * 256 + threadIdx.x;
    if (i >= n) return;
    int4 c = coords[i];
    unsigned k = k23_of(c.x, c.y, c.z, c.w);
    unsigned w = k >> 5, b = k & 31u;
    unsigned mw = maskbm[w];
    if ((mw >> b) & 1u) {
      unsigned j = maskpre[w] + __popc(mw & ((1u << b) - 1u));
      unsigned off = (((unsigned)c.y & 1u) << 2) | (((unsigned)c.z & 1u) << 1) |
                     ((unsigned)c.w & 1u);
      clist[j * 8u + off] = (unsigned)i + 1u;  // row + 1 (0 = absent)
    }
    return;
  }
  if ((int)blockIdx.x < nbN + (int)NBLK2) {
    unsigned w = (blockIdx.x - nbN) * 256u + threadIdx.x;
    unsigned bits = parbm[w];
    if (!bits) return;
    unsigned mb = maskbm[w];
    unsigned r = parpre[w];
    unsigned j = maskpre[w];
    while (bits) {
      unsigned b = (unsigned)__ffs((int)bits) - 1u;
      bits &= bits - 1u;
      unsigned k = (w << 5) | b;
      float bb = (float)(k >> 21);
      float x = (float)(((k >> 14) & 127u) << 1);
      float y = (float)(((k >> 7) & 127u) << 1);
      float z = (float)((k & 127u) << 1);
      out_coords[r] = make_float4(bb, x, y, z);
      if ((mb >> b) & 1u) {
        out_mask[r] = 1.0f;
        mrow[j++] = r;
      }
      r++;
    }
    return;
  }
  // tail: rows [P, N) get coords = -1
  unsigned P = counter[1];
  unsigned idx = (blockIdx.x - nbN - NBLK2) * 256u + threadIdx.x;
  unsigned ntail = (unsigned)n - P;
  float4 m1 = make_float4(-1.f, -1.f, -1.f, -1.f);
  for (unsigned i = idx; i < ntail; i += 64u * 256u) out_coords[P + i] = m1;
}

// ---- conv: W in LDS; one wave per masked parent; children direct from clist ----
// 1024 threads (16 waves), 64 KB LDS -> 2 blocks/CU; min 8 waves/EU.
__global__ __launch_bounds__(1024, 8) void conv_lds(const float* __restrict__ feats,
                                                    const float* __restrict__ Wg,
                                                    const float* __restrict__ bias,
                                                    const unsigned* __restrict__ clist,
                                                    const unsigned* __restrict__ mrow,
                                                    const unsigned* __restrict__ counter,
                                                    float* __restrict__ out_feats) {
  __shared__ float lw[16384];                // all of W: 8*32*64 floats = 64 KB
  for (unsigned t = threadIdx.x; t < 4096u; t += 1024u)
    ((float4*)lw)[t] = ((const float4*)Wg)[t];
  __syncthreads();

  unsigned lane = threadIdx.x & 63u;
  unsigned wave = blockIdx.x * 16u + (threadIdx.x >> 6);
  unsigned nwaves = gridDim.x * 16u;
  unsigned M = counter[0];
  float bv = bias[lane];
  for (unsigned j = wave; j < M; j += nwaves) {
    unsigned r = mrow[j];                    // uniform load -> broadcast
    uint4 c0 = *(const uint4*)(clist + (size_t)j * 8u);
    uint4 c1 = *(const uint4*)(clist + (size_t)j * 8u + 4u);
    unsigned cs[8] = {c0.x, c0.y, c0.z, c0.w, c1.x, c1.y, c1.z, c1.w};
    float acc = bv;
#pragma unroll
    for (int i = 0; i < 8; i++) {
      unsigned v = (unsigned)__builtin_amdgcn_readfirstlane((int)cs[i]);
      if (v) {                               // wave-uniform branch
        const float* f = feats + (size_t)(v - 1u) * 32u;   // SGPR base -> s_load
        const float* wl = lw + i * 2048 + lane;
#pragma unroll
        for (int k = 0; k < 32; k++) acc = fmaf(f[k], wl[k * 64], acc);
      }
    }
    out_feats[(size_t)r * 64u + lane] = acc;
  }
}

extern "C" void kernel_launch(void* const* d_in, const int* in_sizes, int n_in,
                              void* d_out, int out_size, void* d_ws, size_t ws_size,
                              hipStream_t stream) {
  const float* feats = (const float*)d_in[0];
  const float* W     = (const float*)d_in[1];
  const float* bias  = (const float*)d_in[2];
  const int4*  coords = (const int4*)d_in[3];
  const int4*  ref    = (const int4*)d_in[4];
  int N    = in_sizes[0] / 32;
  int NREF = in_sizes[4] / 4;

  float* out_coords = (float*)d_out;
  float* out_feats  = out_coords + (size_t)N * 4;
  float* out_mask   = out_feats + (size_t)N * 64;

  char* ws = (char*)d_ws;
  unsigned* parbm   = (unsigned*)(ws);                    // 1 MB
  unsigned* refbm   = (unsigned*)(ws + (1u << 20));       // 1 MB (becomes maskbm)
  unsigned* maskbm  = refbm;
  unsigned* clist   = (unsigned*)(ws + (2u << 20));       // 13 MB (used: M*8 u32)
  unsigned* parpre  = (unsigned*)(ws + (15u << 20));      // 1 MB
  unsigned* maskpre = (unsigned*)(ws + (16u << 20));      // 1 MB
  unsigned* mrow    = (unsigned*)(ws + (17u << 20));      // 2 MB (M u32 used)
  unsigned* bsums   = (unsigned*)(ws + (19u << 20));            // 2*1024 u32
  unsigned* counter = (unsigned*)(ws + (19u << 20) + 16384);    // 2 u32

  int nbN = (N + 255) / 256;

  // 1) tiny fill: parbm+refbm (2 MB) = 0
  fill_ws<<<64, 256, 0, stream>>>((f4_native*)ws, (size_t)(2u << 20) / 16u);
  // 2) fused: bitmap build + 264 MB out feats+mask zero-fill (fill hides atomics)
  build_fill<<<2048, 256, 0, stream>>>(coords, N, ref, NREF, parbm, refbm,
                                       (f4_native*)out_feats,
                                       (size_t)N * 65u * 4u / 16u);
  // 3) popcount block sums + mask AND
  pop2<<<NBLK2, 256, 0, stream>>>(parbm, refbm, bsums);
  // 4) prefixes (self-scanned) + clist zero + totals
  prefix2b<<<NBLK2, 256, 0, stream>>>(parbm, maskbm, bsums, parpre, maskpre, clist,
                                      counter);
  // 5) input->clist scatter + emit coords/mask/mrow + coords tail fill
  scatter_emit<<<nbN + NBLK2 + 64, 256, 0, stream>>>(coords, N, parbm, parpre, maskbm,
                                                     maskpre, counter, clist, mrow,
                                                     (float4*)out_coords, out_mask, nbN);
  // 6) conv
  conv_lds<<<512, 1024, 0, stream>>>(feats, W, bias, clist, mrow, counter, out_feats);
}